// Round 9
// baseline (76.364 us; speedup 1.0000x reference)
//
#include <hip/hip_runtime.h>

#define PHI     1.618033988749895f
#define INV_PHI 0.6180339887498949f

typedef _Float16 f16x8 __attribute__((ext_vector_type(8)));
typedef float    f32x4 __attribute__((ext_vector_type(4)));

__device__ __forceinline__ float phi_spiral(float v) {
    // sigmoid(v/phi) * (v*phi/(1+|v|)) = v*phi / ((1+e^{-v/phi})(1+|v|))
    float e = __expf(-v * INV_PHI);
    float d = (1.0f + e) * (1.0f + fabsf(v));
    return __fdividef(v * PHI, d);
}

// ---------------- workspace layout ----------------
#define WS_B1 0
#define WS_B2 16384
#define WS_B3 20480
#define WS_BIAS_BYTES 65536

// B-fragment lane layout for v_mfma_f32_16x16x32_f16 (verified, m89-m103):
// lane holds B[k][n], n = lane&15, k = (lane>>4)*8 + j.
__global__ void prep_kernel(
    const float* __restrict__ W_in, const float* __restrict__ b_in,
    const float* __restrict__ Wn,   const float* __restrict__ bn,
    const float* __restrict__ W_int,const float* __restrict__ b_int,
    _Float16* __restrict__ wsh, float* __restrict__ wsb)
{
    if (blockIdx.x == 11) {                      // padded biases
        const int t = threadIdx.x;
        if (t < 64)       wsb[t] = (t < 49)        ? b_in[t]        : 0.f;
        else if (t < 128) wsb[t] = (t - 64 < 49)   ? bn[t - 64]     : 0.f;
        else if (t < 160) wsb[t] = (t - 128 < 21)  ? b_int[t - 128] : 0.f;
        return;
    }
    const int g    = blockIdx.x * 256 + threadIdx.x;   // 0..2815
    const int lane = g & 63;
    const int fid  = g >> 6;                            // 0..43
    const int lr = lane & 15, lk = lane >> 4;
    f16x8 o;
    if (fid < 32) {                       // stage 1: W_in[49,256]
        const int ks = fid >> 2, nt = fid & 3;
        const int n = nt * 16 + lr, kb = ks * 32 + lk * 8;
#pragma unroll 8
        for (int j = 0; j < 8; ++j) {
            const int k = kb + j;
            o[j] = (_Float16)((n < 49) ? W_in[n * 256 + k] : 0.f);
        }
        *reinterpret_cast<f16x8*>(wsh + WS_B1 + (size_t)(fid * 64 + lane) * 8) = o;
    } else if (fid < 40) {                // stage 2: Wn flat [49,49]
        const int f = fid - 32, ks = f >> 2, nt = f & 3;
        const int n = nt * 16 + lr, kb = ks * 32 + lk * 8;
#pragma unroll 8
        for (int j = 0; j < 8; ++j) {
            const int k = kb + j;
            o[j] = (_Float16)((n < 49 && k < 49) ? Wn[n * 49 + k] : 0.f);
        }
        *reinterpret_cast<f16x8*>(wsh + WS_B2 + (size_t)(f * 64 + lane) * 8) = o;
    } else {                              // stage 3: W_int[21,49]
        const int f = fid - 40, ks = f >> 1, nt = f & 1;
        const int n = nt * 16 + lr, kb = ks * 32 + lk * 8;
#pragma unroll 8
        for (int j = 0; j < 8; ++j) {
            const int k = kb + j;
            o[j] = (_Float16)((n < 21 && k < 49) ? W_int[n * 49 + k] : 0.f);
        }
        *reinterpret_cast<f16x8*>(wsh + WS_B3 + (size_t)(f * 64 + lane) * 8) = o;
    }
}

// 256 threads = 4 waves; 64 rows/block (16 rows/wave, no mi loop); grid 4096.
// waves_per_eu(8,8): allocator cap = 512/8 = 64 VGPR; stage-1 live set ~54
// (acc 16 + bf 16 + lo/hi 8 + a 4 + addr ~10) -> spill-free at 8 waves/SIMD
// (R8 had 6). LDS 9.2 KB/block -> 8 blocks/CU = 74 KB, not limiting.
__global__ __launch_bounds__(256)
__attribute__((amdgpu_waves_per_eu(8, 8)))
void seven_neurons_mfma(
    const float* __restrict__ x,
    const _Float16* __restrict__ wsh, const float* __restrict__ wsb,
    const float* __restrict__ gamma, const float* __restrict__ beta,
    const float* __restrict__ W_out, const float* __restrict__ b_out,
    float* __restrict__ out)
{
    __shared__ __align__(16) unsigned char ldsraw[64 * 72 * 2];
    _Float16* ldsH = reinterpret_cast<_Float16*>(ldsraw);
    float*    ldsF = reinterpret_cast<float*>(ldsraw);

    const int t = threadIdx.x;
    const int lane = t & 63, wv = t >> 6;
    const int lr = lane & 15, lk = lane >> 4;
    const size_t row0 = (size_t)blockIdx.x * 64;

    // ---- stage 1: h[64,49] = spiral(x @ W_in^T + b1), MFMA over K=256
    f32x4 acc1[4];
#pragma unroll 4
    for (int ni = 0; ni < 4; ++ni) acc1[ni] = (f32x4){0.f, 0.f, 0.f, 0.f};

    // per-lane A base: row = row0 + wv*16 + lr, col base = lk*8
    const float* xa = x + (row0 + wv * 16 + lr) * 256 + lk * 8;

#pragma unroll 8
    for (int ks = 0; ks < 8; ++ks) {
        f16x8 bf[4];
#pragma unroll 4
        for (int nt = 0; nt < 4; ++nt)
            bf[nt] = *reinterpret_cast<const f16x8*>(
                wsh + WS_B1 + (size_t)((ks * 4 + nt) * 64 + lane) * 8);
        const float4 lo = *reinterpret_cast<const float4*>(xa + ks * 32);
        const float4 hi = *reinterpret_cast<const float4*>(xa + ks * 32 + 4);
        const f16x8 a = { (_Float16)lo.x, (_Float16)lo.y, (_Float16)lo.z, (_Float16)lo.w,
                          (_Float16)hi.x, (_Float16)hi.y, (_Float16)hi.z, (_Float16)hi.w };
#pragma unroll 4
        for (int nt = 0; nt < 4; ++nt)
            acc1[nt] = __builtin_amdgcn_mfma_f32_16x16x32_f16(
                a, bf[nt], acc1[nt], 0, 0, 0);
    }

    // epilogue 1: h -> LDS fp16 [64][72], cols 49..63 exact 0 (wave-private:
    // C/D row = lk*4+r spans 0..15 -> rows wv*16..wv*16+15)
    {
        float b1v[4];
#pragma unroll 4
        for (int nt = 0; nt < 4; ++nt) b1v[nt] = wsb[nt * 16 + lr];
#pragma unroll 4
        for (int nt = 0; nt < 4; ++nt)
#pragma unroll 4
            for (int r = 0; r < 4; ++r) {
                const int row = wv * 16 + lk * 4 + r;
                const float v = phi_spiral(acc1[nt][r] + b1v[nt]);
                ldsH[row * 72 + nt * 16 + lr] = (_Float16)v;
            }
    }

    // ---- stage 2: comb[64,49] = spiral(h @ Wn^T + b2), K=64
    f32x4 acc2[4];
#pragma unroll 4
    for (int ni = 0; ni < 4; ++ni) acc2[ni] = (f32x4){0.f, 0.f, 0.f, 0.f};
#pragma unroll 2
    for (int ks = 0; ks < 2; ++ks) {
        f16x8 bf[4];
#pragma unroll 4
        for (int nt = 0; nt < 4; ++nt)
            bf[nt] = *reinterpret_cast<const f16x8*>(
                wsh + WS_B2 + (size_t)((ks * 4 + nt) * 64 + lane) * 8);
        const f16x8 a = *reinterpret_cast<const f16x8*>(
            &ldsH[(wv * 16 + lr) * 72 + ks * 32 + lk * 8]);
#pragma unroll 4
        for (int nt = 0; nt < 4; ++nt)
            acc2[nt] = __builtin_amdgcn_mfma_f32_16x16x32_f16(
                a, bf[nt], acc2[nt], 0, 0, 0);
    }
    // epilogue 2: comb overwrites h (own rows; in-wave DS ordering suffices)
    {
        float b2v[4];
#pragma unroll 4
        for (int nt = 0; nt < 4; ++nt) b2v[nt] = wsb[64 + nt * 16 + lr];
#pragma unroll 4
        for (int nt = 0; nt < 4; ++nt)
#pragma unroll 4
            for (int r = 0; r < 4; ++r) {
                const int row = wv * 16 + lk * 4 + r;
                const float v = phi_spiral(acc2[nt][r] + b2v[nt]);
                ldsH[row * 72 + nt * 16 + lr] = (_Float16)v;
            }
    }

    // ---- stage 3: integ[64,21] = spiral(comb @ W_int^T + b3), K=64, N=32
    f32x4 acc3[2];
#pragma unroll 2
    for (int ni = 0; ni < 2; ++ni) acc3[ni] = (f32x4){0.f, 0.f, 0.f, 0.f};
#pragma unroll 2
    for (int ks = 0; ks < 2; ++ks) {
        f16x8 bf[2];
#pragma unroll 2
        for (int nt = 0; nt < 2; ++nt)
            bf[nt] = *reinterpret_cast<const f16x8*>(
                wsh + WS_B3 + (size_t)((ks * 2 + nt) * 64 + lane) * 8);
        const f16x8 a = *reinterpret_cast<const f16x8*>(
            &ldsH[(wv * 16 + lr) * 72 + ks * 32 + lk * 8]);
#pragma unroll 2
        for (int nt = 0; nt < 2; ++nt)
            acc3[nt] = __builtin_amdgcn_mfma_f32_16x16x32_f16(
                a, bf[nt], acc3[nt], 0, 0, 0);
    }
    __syncthreads();   // all ldsH reads done before aliased ldsF overwrite
    // epilogue 3: integ -> LDS fp32 [64][25] (stride 25: conflict-free)
    {
        float b3v[2];
#pragma unroll 2
        for (int nt = 0; nt < 2; ++nt) b3v[nt] = wsb[128 + nt * 16 + lr];
#pragma unroll 2
        for (int nt = 0; nt < 2; ++nt)
#pragma unroll 4
            for (int r = 0; r < 4; ++r) {
                const int col = nt * 16 + lr;
                const int row = wv * 16 + lk * 4 + r;
                if (col < 21)
                    ldsF[row * 25 + col] =
                        phi_spiral(acc3[nt][r] + b3v[nt]);
            }
    }
    __syncthreads();

    // ---- LayerNorm(21) + out: 4 threads/row (r = t>>2, p = t&3);
    // mean/var computed redundantly x4 (cheap); store = 1 dword/thread,
    // thread t -> out[row0*4 + t]: fully coalesced.
    {
        const int r = t >> 2, p = t & 3;
        const float* my = ldsF + r * 25;
        float v[21];
#pragma unroll 21
        for (int o = 0; o < 21; ++o) v[o] = my[o];
        float mu = 0.f;
#pragma unroll 21
        for (int o = 0; o < 21; ++o) mu += v[o];
        mu *= (1.0f / 21.0f);
        float var = 0.f;
#pragma unroll 21
        for (int o = 0; o < 21; ++o) { float d = v[o] - mu; var = fmaf(d, d, var); }
        var *= (1.0f / 21.0f);
        const float rs = rsqrtf(var + 1e-5f);
        float acc = b_out[p];
#pragma unroll 21
        for (int o = 0; o < 21; ++o)
            acc = fmaf((v[o] - mu) * rs * gamma[o] + beta[o], W_out[p * 21 + o], acc);
        out[row0 * 4 + t] = acc;
    }
}

extern "C" void kernel_launch(void* const* d_in, const int* in_sizes, int n_in,
                              void* d_out, int out_size, void* d_ws, size_t ws_size,
                              hipStream_t stream) {
    const float* x     = (const float*)d_in[0];
    const float* W_in  = (const float*)d_in[1];
    const float* b_in  = (const float*)d_in[2];
    const float* Wn    = (const float*)d_in[3];
    const float* bn    = (const float*)d_in[4];
    const float* W_int = (const float*)d_in[5];
    const float* b_int = (const float*)d_in[6];
    const float* gamma = (const float*)d_in[7];
    const float* beta  = (const float*)d_in[8];
    const float* W_out = (const float*)d_in[9];
    const float* b_out = (const float*)d_in[10];
    float* out = (float*)d_out;

    _Float16* wsh = (_Float16*)d_ws;
    float*    wsb = (float*)((char*)d_ws + WS_BIAS_BYTES);

    prep_kernel<<<12, 256, 0, stream>>>(W_in, b_in, Wn, bn, W_int, b_int, wsh, wsb);

    const int B = in_sizes[0] / 256;          // 262144, multiple of 64
    seven_neurons_mfma<<<B / 64, 256, 0, stream>>>(
        x, wsh, wsb, gamma, beta, W_out, b_out, out);
}

// Round 11
// 63.193 us; speedup vs baseline: 1.2084x; 1.2084x over previous
//
#include <hip/hip_runtime.h>

#define PHI     1.618033988749895f
#define INV_PHI 0.6180339887498949f

typedef _Float16 f16x8 __attribute__((ext_vector_type(8)));
typedef float    f32x4 __attribute__((ext_vector_type(4)));

typedef const __attribute__((address_space(1))) void gas_void;
typedef __attribute__((address_space(3))) void las_void;

__device__ __forceinline__ float phi_spiral(float v) {
    // sigmoid(v/phi) * (v*phi/(1+|v|)) = v*phi / ((1+e^{-v/phi})(1+|v|))
    float e = __expf(-v * INV_PHI);
    float d = (1.0f + e) * (1.0f + fabsf(v));
    return __fdividef(v * PHI, d);
}

// async global->LDS, 16B/lane. LDS dest must be WAVE-UNIFORM base
// (HW writes base + lane*16); global src is per-lane (m104).
__device__ __forceinline__ void cp16(const void* g, void* l) {
    __builtin_amdgcn_global_load_lds((gas_void*)g, (las_void*)l, 16, 0, 0);
}

// ---------------- workspace layout ----------------
#define WS_B1 0
#define WS_B2 16384
#define WS_B3 20480
#define WS_BIAS_BYTES 65536

// B-fragment lane layout for v_mfma_f32_16x16x32_f16 (verified, m89-m103):
// lane holds B[k][n], n = lane&15, k = (lane>>4)*8 + j.
__global__ void prep_kernel(
    const float* __restrict__ W_in, const float* __restrict__ b_in,
    const float* __restrict__ Wn,   const float* __restrict__ bn,
    const float* __restrict__ W_int,const float* __restrict__ b_int,
    _Float16* __restrict__ wsh, float* __restrict__ wsb)
{
    if (blockIdx.x == 11) {                      // padded biases
        const int t = threadIdx.x;
        if (t < 64)       wsb[t] = (t < 49)        ? b_in[t]        : 0.f;
        else if (t < 128) wsb[t] = (t - 64 < 49)   ? bn[t - 64]     : 0.f;
        else if (t < 160) wsb[t] = (t - 128 < 21)  ? b_int[t - 128] : 0.f;
        return;
    }
    const int g    = blockIdx.x * 256 + threadIdx.x;   // 0..2815
    const int lane = g & 63;
    const int fid  = g >> 6;                            // 0..43
    const int lr = lane & 15, lk = lane >> 4;
    f16x8 o;
    if (fid < 32) {                       // stage 1: W_in[49,256]
        const int ks = fid >> 2, nt = fid & 3;
        const int n = nt * 16 + lr, kb = ks * 32 + lk * 8;
#pragma unroll 8
        for (int j = 0; j < 8; ++j) {
            const int k = kb + j;
            o[j] = (_Float16)((n < 49) ? W_in[n * 256 + k] : 0.f);
        }
        *reinterpret_cast<f16x8*>(wsh + WS_B1 + (size_t)(fid * 64 + lane) * 8) = o;
    } else if (fid < 40) {                // stage 2: Wn flat [49,49]
        const int f = fid - 32, ks = f >> 2, nt = f & 3;
        const int n = nt * 16 + lr, kb = ks * 32 + lk * 8;
#pragma unroll 8
        for (int j = 0; j < 8; ++j) {
            const int k = kb + j;
            o[j] = (_Float16)((n < 49 && k < 49) ? Wn[n * 49 + k] : 0.f);
        }
        *reinterpret_cast<f16x8*>(wsh + WS_B2 + (size_t)(f * 64 + lane) * 8) = o;
    } else {                              // stage 3: W_int[21,49]
        const int f = fid - 40, ks = f >> 1, nt = f & 1;
        const int n = nt * 16 + lr, kb = ks * 32 + lk * 8;
#pragma unroll 8
        for (int j = 0; j < 8; ++j) {
            const int k = kb + j;
            o[j] = (_Float16)((n < 21 && k < 49) ? W_int[n * 49 + k] : 0.f);
        }
        *reinterpret_cast<f16x8*>(wsh + WS_B3 + (size_t)(f * 64 + lane) * 8) = o;
    }
}

// 256 thr = 4 waves, 64 rows/block (16 rows/wave), grid 4096.
// LDS 48 KB -> 3 blocks/CU (12 waves/CU):
//   [0,32K)   B1 fragments, FULL 32 KB (R10 bug: staged only 16 KB and read
//             32 KB -> garbage -> NaN). Stage-1 loop's only VMEM = x-DMAs.
//   [32K+wv*4K, +4K) per-wave slot: x chunk dbuf (2 x 2 KB) in stage 1,
//             then H fp16 [16][72], then integ fp32 [16][25] overlay.
// x chunk LDS is written LINEARLY by DMA; bank conflicts on the stride-128B
// A-frag reads are fixed by PRE-SWIZZLING the global source (granule ^= row&7)
// and XORing the same involution into the read offsets (rule #21).
// Pipeline: vmcnt(2) = chunk k ready, k+1 in flight; lgkmcnt(0) WAR fence;
// issue chunk k+2 into parity k&1; 4 MFMA. vmcnt never 0 until last chunk.
__global__ __launch_bounds__(256)
__attribute__((amdgpu_waves_per_eu(3, 8)))
void seven_neurons_mfma(
    const float* __restrict__ x,
    const _Float16* __restrict__ wsh, const float* __restrict__ wsb,
    const float* __restrict__ gamma, const float* __restrict__ beta,
    const float* __restrict__ W_out, const float* __restrict__ b_out,
    float* __restrict__ out)
{
    __shared__ __align__(16) unsigned char lds[32768 + 4 * 4096];

    const int t = threadIdx.x;
    const int lane = t & 63, wv = t >> 6;
    const int lr = lane & 15, lk = lane >> 4;
    const size_t row0 = (size_t)blockIdx.x * 64;

    unsigned char* ldsB1 = lds;
    unsigned char* slot  = lds + 32768 + wv * 4096;

    // ---- biases first (oldest in vmcnt queue; drained by prologue vmcnt(4))
    float b1v[4], b2v[4], b3v[2];
#pragma unroll 4
    for (int nt = 0; nt < 4; ++nt) { b1v[nt] = wsb[nt * 16 + lr]; b2v[nt] = wsb[64 + nt * 16 + lr]; }
#pragma unroll 2
    for (int nt = 0; nt < 2; ++nt) b3v[nt] = wsb[128 + nt * 16 + lr];

    // ---- prologue: B1 -> LDS (8 KB/wave, 8 DMAs), then x chunks 0,1
    const unsigned char* wsrc = (const unsigned char*)wsh;   // B1 at byte 0
#pragma unroll 8
    for (int q = 0; q < 8; ++q)
        cp16(wsrc + wv * 8192 + q * 1024 + lane * 16,
             ldsB1 + wv * 8192 + q * 1024);

    // x source, PRE-SWIZZLED: staging lane i covers LDS row i>>3 (+8 for the
    // second DMA), granule i&7. Linear DMA dest => lane must FETCH logical
    // granule (i&7)^(row&7) so that reads can un-swizzle with the same XOR.
    const int srow = lane >> 3;                      // 0..7
    const int sgr  = (lane & 7) ^ (srow & 7);        // swizzled granule
    const float* xsrc = x + (row0 + wv * 16 + srow) * 256 + sgr * 4;

    cp16(xsrc + 0 * 2048 + 0 * 32, slot + 0 * 2048 + 0 * 1024);   // chunk0 rows 0-7
    cp16(xsrc + 1 * 2048 + 0 * 32, slot + 0 * 2048 + 1 * 1024);   // chunk0 rows 8-15
    cp16(xsrc + 0 * 2048 + 1 * 32, slot + 1 * 2048 + 0 * 1024);   // chunk1 rows 0-7
    cp16(xsrc + 1 * 2048 + 1 * 32, slot + 1 * 2048 + 1 * 1024);   // chunk1 rows 8-15

    asm volatile("s_waitcnt vmcnt(4)" ::: "memory");   // B1+biases done; x0,x1 in flight
    __builtin_amdgcn_sched_barrier(0);
    __builtin_amdgcn_s_barrier();                      // publish B1 (no vmcnt(0) drain)

    // reader offsets (constant per lane): logical row lr, granules 2lk,2lk+1,
    // physical granule = logical ^ (lr&7)
    const int xoff0 = lr * 128 + (((2 * lk)     ^ (lr & 7)) << 4);
    const int xoff1 = lr * 128 + (((2 * lk + 1) ^ (lr & 7)) << 4);

    // ---- stage 1: h[64,49] = spiral(x @ W_in^T + b1), K=256
    f32x4 acc1[4];
#pragma unroll 4
    for (int ni = 0; ni < 4; ++ni) acc1[ni] = (f32x4){0.f, 0.f, 0.f, 0.f};

#pragma unroll
    for (int k = 0; k < 8; ++k) {
        if (k < 7) asm volatile("s_waitcnt vmcnt(2)" ::: "memory");
        else       asm volatile("s_waitcnt vmcnt(0)" ::: "memory");
        __builtin_amdgcn_sched_barrier(0);

        const unsigned char* xc = slot + (k & 1) * 2048;
        const f32x4 r0 = *reinterpret_cast<const f32x4*>(xc + xoff0);
        const f32x4 r1 = *reinterpret_cast<const f32x4*>(xc + xoff1);
        const f16x8 a = { (_Float16)r0[0], (_Float16)r0[1], (_Float16)r0[2], (_Float16)r0[3],
                          (_Float16)r1[0], (_Float16)r1[1], (_Float16)r1[2], (_Float16)r1[3] };

        // WAR fence: chunk-k LDS reads retired before refilling this buffer
        asm volatile("s_waitcnt lgkmcnt(0)" ::: "memory");
        __builtin_amdgcn_sched_barrier(0);
        if (k + 2 < 8) {
            cp16(xsrc + 0 * 2048 + (k + 2) * 32, slot + (k & 1) * 2048 + 0 * 1024);
            cp16(xsrc + 1 * 2048 + (k + 2) * 32, slot + (k & 1) * 2048 + 1 * 1024);
        }

#pragma unroll 4
        for (int nt = 0; nt < 4; ++nt) {
            const f16x8 bf = *reinterpret_cast<const f16x8*>(
                ldsB1 + (size_t)(k * 4 + nt) * 1024 + lane * 16);
            acc1[nt] = __builtin_amdgcn_mfma_f32_16x16x32_f16(a, bf, acc1[nt], 0, 0, 0);
        }
    }

    // epilogue 1: H fp16 [16 rows][72] into own slot (x bufs dead)
    {
        _Float16* H = (_Float16*)slot;
#pragma unroll 4
        for (int nt = 0; nt < 4; ++nt)
#pragma unroll 4
            for (int r = 0; r < 4; ++r) {
                const int row = lk * 4 + r;                  // 0..15
                const float v = phi_spiral(acc1[nt][r] + b1v[nt]);
                H[row * 72 + nt * 16 + lr] = (_Float16)v;
            }
    }

    // ---- stage 2: comb = spiral(h @ Wn^T + b2), K=64 (wave-private)
    f32x4 acc2[4];
#pragma unroll 4
    for (int ni = 0; ni < 4; ++ni) acc2[ni] = (f32x4){0.f, 0.f, 0.f, 0.f};
#pragma unroll 2
    for (int ks = 0; ks < 2; ++ks) {
        const f16x8 a = *reinterpret_cast<const f16x8*>(
            slot + lr * 144 + (ks * 32 + lk * 8) * 2);
#pragma unroll 4
        for (int nt = 0; nt < 4; ++nt) {
            const f16x8 bf = *reinterpret_cast<const f16x8*>(
                wsh + WS_B2 + (size_t)((ks * 4 + nt) * 64 + lane) * 8);
            acc2[nt] = __builtin_amdgcn_mfma_f32_16x16x32_f16(a, bf, acc2[nt], 0, 0, 0);
        }
    }
    {
        _Float16* H = (_Float16*)slot;
#pragma unroll 4
        for (int nt = 0; nt < 4; ++nt)
#pragma unroll 4
            for (int r = 0; r < 4; ++r) {
                const int row = lk * 4 + r;
                const float v = phi_spiral(acc2[nt][r] + b2v[nt]);
                H[row * 72 + nt * 16 + lr] = (_Float16)v;
            }
    }

    // ---- stage 3: integ = spiral(comb @ W_int^T + b3), K=64, N=32
    f32x4 acc3[2];
#pragma unroll 2
    for (int ni = 0; ni < 2; ++ni) acc3[ni] = (f32x4){0.f, 0.f, 0.f, 0.f};
#pragma unroll 2
    for (int ks = 0; ks < 2; ++ks) {
        const f16x8 a = *reinterpret_cast<const f16x8*>(
            slot + lr * 144 + (ks * 32 + lk * 8) * 2);
#pragma unroll 2
        for (int nt = 0; nt < 2; ++nt) {
            const f16x8 bf = *reinterpret_cast<const f16x8*>(
                wsh + WS_B3 + (size_t)((ks * 2 + nt) * 64 + lane) * 8);
            acc3[nt] = __builtin_amdgcn_mfma_f32_16x16x32_f16(a, bf, acc3[nt], 0, 0, 0);
        }
    }
    // epilogue 3: integ fp32 [16][25] into own slot
    {
        float* F = (float*)slot;
#pragma unroll 2
        for (int nt = 0; nt < 2; ++nt)
#pragma unroll 4
            for (int r = 0; r < 4; ++r) {
                const int col = nt * 16 + lr;
                const int row = lk * 4 + r;
                if (col < 21)
                    F[row * 25 + col] = phi_spiral(acc3[nt][r] + b3v[nt]);
            }
    }
    __syncthreads();   // cross-wave: LN reads other waves' slots

    // ---- LayerNorm(21) + out: 4 threads/row (r = t>>2, p = t&3)
    {
        const int r = t >> 2, p = t & 3;
        const float* my = (const float*)(lds + 32768 + (r >> 4) * 4096) + (r & 15) * 25;
        float v[21];
#pragma unroll 21
        for (int o = 0; o < 21; ++o) v[o] = my[o];
        float mu = 0.f;
#pragma unroll 21
        for (int o = 0; o < 21; ++o) mu += v[o];
        mu *= (1.0f / 21.0f);
        float var = 0.f;
#pragma unroll 21
        for (int o = 0; o < 21; ++o) { float d = v[o] - mu; var = fmaf(d, d, var); }
        var *= (1.0f / 21.0f);
        const float rs = rsqrtf(var + 1e-5f);
        float acc = b_out[p];
#pragma unroll 21
        for (int o = 0; o < 21; ++o)
            acc = fmaf((v[o] - mu) * rs * gamma[o] + beta[o], W_out[p * 21 + o], acc);
        out[row0 * 4 + t] = acc;
    }
}

extern "C" void kernel_launch(void* const* d_in, const int* in_sizes, int n_in,
                              void* d_out, int out_size, void* d_ws, size_t ws_size,
                              hipStream_t stream) {
    const float* x     = (const float*)d_in[0];
    const float* W_in  = (const float*)d_in[1];
    const float* b_in  = (const float*)d_in[2];
    const float* Wn    = (const float*)d_in[3];
    const float* bn    = (const float*)d_in[4];
    const float* W_int = (const float*)d_in[5];
    const float* b_int = (const float*)d_in[6];
    const float* gamma = (const float*)d_in[7];
    const float* beta  = (const float*)d_in[8];
    const float* W_out = (const float*)d_in[9];
    const float* b_out = (const float*)d_in[10];
    float* out = (float*)d_out;

    _Float16* wsh = (_Float16*)d_ws;
    float*    wsb = (float*)((char*)d_ws + WS_BIAS_BYTES);

    prep_kernel<<<12, 256, 0, stream>>>(W_in, b_in, Wn, bn, W_int, b_int, wsh, wsb);

    const int B = in_sizes[0] / 256;          // 262144, multiple of 64
    seven_neurons_mfma<<<B / 64, 256, 0, stream>>>(
        x, wsh, wsb, gamma, beta, W_out, b_out, out);
}